// Round 7
// baseline (86.676 us; speedup 1.0000x reference)
//
#include <hip/hip_runtime.h>
#include <stdint.h>

#define NB   8
#define NN   2048
#define FIN  128
#define FOUT 64

__device__ __forceinline__ uint32_t rotl32(uint32_t x, uint32_t r) {
  return (x << r) | (x >> (32u - r));
}

// JAX threefry2x32 with key = (0, 42)
__device__ __forceinline__ void threefry_0_42(uint32_t x0, uint32_t x1,
                                              uint32_t& o0, uint32_t& o1) {
  const uint32_t k0 = 0u, k1 = 42u;
  const uint32_t k2 = 0x1BD11BDAu ^ k0 ^ k1;
  x0 += k0; x1 += k1;
#define TFR(r) { x0 += x1; x1 = rotl32(x1, r); x1 ^= x0; }
  TFR(13u) TFR(15u) TFR(26u) TFR(6u)   x0 += k1; x1 += k2 + 1u;
  TFR(17u) TFR(29u) TFR(16u) TFR(24u)  x0 += k2; x1 += k0 + 2u;
  TFR(13u) TFR(15u) TFR(26u) TFR(6u)   x0 += k0; x1 += k1 + 3u;
  TFR(17u) TFR(29u) TFR(16u) TFR(24u)  x0 += k1; x1 += k2 + 4u;
  TFR(13u) TFR(15u) TFR(26u) TFR(6u)   x0 += k2; x1 += k0 + 5u;
#undef TFR
  o0 = x0; o1 = x1;
}

// Partitionable threefry: bits = o0^o1 of threefry(key, 0, v); keep iff bit31==0.
__device__ __forceinline__ bool keep_bit(uint32_t v) {
  uint32_t o0, o1;
  threefry_0_42(0u, v, o0, o1);
  return !((o0 ^ o1) >> 31);
}

// Kernel A: Wh = h @ W, Wh1 = Wh@a[:64], Wh2 = Wh@a[64:]
// 4 rows/wave, scalar accumulators (W LDS read amortized x4, no spill risk).
__global__ __launch_bounds__(256) void wh_kernel(
    const float* __restrict__ h, const float* __restrict__ W,
    const float* __restrict__ a, float* __restrict__ Wh,
    float* __restrict__ Wh1, float* __restrict__ Wh2) {
  __shared__ __align__(16) float wLds[FIN * FOUT];   // 32 KB
  __shared__ __align__(16) float hLds[16][FIN];      // 8 KB
  const int t = threadIdx.x;
  const int wv = t >> 6, lane = t & 63;
  const int rbase = blockIdx.x * 16;
  {
    const float4* W4 = reinterpret_cast<const float4*>(W);
    float4* wL4 = reinterpret_cast<float4*>(wLds);
    for (int idx = t; idx < FIN * FOUT / 4; idx += 256) wL4[idx] = W4[idx];
    const float4* h4 = reinterpret_cast<const float4*>(h + (size_t)rbase * FIN);
    float4* hL4 = reinterpret_cast<float4*>(&hLds[0][0]);
    for (int idx = t; idx < 16 * FIN / 4; idx += 256) hL4[idx] = h4[idx];
  }
  __syncthreads();
  const int r0 = wv * 4;
  float acc0 = 0.f, acc1 = 0.f, acc2 = 0.f, acc3 = 0.f;
#pragma unroll 4
  for (int k = 0; k < FIN; ++k) {
    const float w = wLds[k * FOUT + lane];   // lanes consecutive: 2-way, free
    acc0 += hLds[r0 + 0][k] * w;             // broadcasts
    acc1 += hLds[r0 + 1][k] * w;
    acc2 += hLds[r0 + 2][k] * w;
    acc3 += hLds[r0 + 3][k] * w;
  }
  const float a1 = a[lane], a2 = a[FOUT + lane];
  float accs[4] = {acc0, acc1, acc2, acc3};
#pragma unroll
  for (int r = 0; r < 4; ++r) {
    const int row = rbase + r0 + r;
    Wh[(size_t)row * FOUT + lane] = accs[r];
    float x1 = accs[r] * a1, x2 = accs[r] * a2;
#pragma unroll
    for (int off = 32; off >= 1; off >>= 1) {
      x1 += __shfl_xor(x1, off);
      x2 += __shfl_xor(x2, off);
    }
    if (lane == 0) { Wh1[row] = x1; Wh2[row] = x2; }
  }
}

// Kernel B: ONE WAVE per (b,i) row. No __syncthreads, no LDS, no atomics.
//   load adj row + Wh2 row (8x int4 + 8x float4), mask to ww in regs;
//   shfl-max -> mW; e = LR(wh1+ww); p = exp(e - me) (underflow handles tail);
//   shfl-sum -> s; ballot-walk survivors (p>1e-10, ~1-3/row): wave-uniform
//   threefry keep, coalesced 256 B Wh row load, fma; store out row.
__global__ __launch_bounds__(256) void attn_kernel(
    const int* __restrict__ adj, const float* __restrict__ Wh,
    const float* __restrict__ Wh1, const float* __restrict__ Wh2,
    float* __restrict__ out) {
  const int t = threadIdx.x;
  const int wv = t >> 6, lane = t & 63;
  const int r = blockIdx.x * 4 + wv;     // global row = b*NN + i, [0, 16384)
  const int b = r >> 11;

  const float wh1 = Wh1[r];
  const int4*   adjv = reinterpret_cast<const int4*>(adj) + (size_t)r * (NN / 4);
  const float4* wh2v = reinterpret_cast<const float4*>(Wh2) + (size_t)b * (NN / 4);

  // pv: ww -> p, in place. slot (c,e) <-> j = c*256 + lane*4 + e
  float pv[8][4];
  float mW = -3.0e38f;
#pragma unroll
  for (int c = 0; c < 8; ++c) {
    const int4   av = adjv[c * 64 + lane];
    const float4 w2 = wh2v[c * 64 + lane];
    pv[c][0] = (av.x > 0) ? w2.x : -1.0e30f;
    pv[c][1] = (av.y > 0) ? w2.y : -1.0e30f;
    pv[c][2] = (av.z > 0) ? w2.z : -1.0e30f;
    pv[c][3] = (av.w > 0) ? w2.w : -1.0e30f;
    mW = fmaxf(mW, fmaxf(fmaxf(pv[c][0], pv[c][1]), fmaxf(pv[c][2], pv[c][3])));
  }
#pragma unroll
  for (int off = 1; off < 64; off <<= 1) mW = fmaxf(mW, __shfl_xor(mW, off));

  const float me_arg = wh1 + mW;
  const float me = (me_arg < 0.f) ? 0.2f * me_arg : me_arg;   // row max of e

  float s = 0.f;
#pragma unroll
  for (int c = 0; c < 8; ++c) {
#pragma unroll
    for (int e = 0; e < 4; ++e) {
      float z = wh1 + pv[c][e];
      z = (z < 0.f) ? 0.2f * z : z;
      const float p = __expf(z - me);    // masked (-1e30) underflows to 0
      s += p;
      pv[c][e] = p;
    }
  }
#pragma unroll
  for (int off = 1; off < 64; off <<= 1) s += __shfl_xor(s, off);
  const float inv = 2.0f / s;            // dropout 1/(1-p)=2 folded in

  // ballot walk over survivors
  float acc = 0.f;
  const uint32_t vbase = (uint32_t)r << 11;
#pragma unroll
  for (int c = 0; c < 8; ++c) {
#pragma unroll
    for (int e = 0; e < 4; ++e) {
      unsigned long long msk = __ballot(pv[c][e] > 1e-10f);
      while (msk) {
        const int src = __builtin_ctzll(msk);
        msk &= msk - 1;
        const int j = c * 256 + src * 4 + e;
        if (keep_bit(vbase | (uint32_t)j)) {       // wave-uniform
          const float cc = __shfl(pv[c][e], src) * inv;
          acc += cc * Wh[((size_t)(b * NN + j)) * FOUT + lane];
        }
      }
    }
  }
  out[(size_t)r * FOUT + lane] = acc;
}

extern "C" void kernel_launch(void* const* d_in, const int* in_sizes, int n_in,
                              void* d_out, int out_size, void* d_ws, size_t ws_size,
                              hipStream_t stream) {
  const float* h   = (const float*)d_in[0];
  const int*   adj = (const int*)d_in[1];
  const float* W   = (const float*)d_in[2];
  const float* a   = (const float*)d_in[3];
  float* out = (float*)d_out;
  float* ws  = (float*)d_ws;

  float* Wh  = ws;                                 // 16384*64 floats
  float* Wh1 = ws + (size_t)NB * NN * FOUT;        // 16384
  float* Wh2 = Wh1 + NB * NN;                      // 16384

  wh_kernel<<<dim3((NB * NN) / 16), dim3(256), 0, stream>>>(h, W, a, Wh, Wh1, Wh2);
  attn_kernel<<<dim3((NB * NN) / 4), dim3(256), 0, stream>>>(adj, Wh, Wh1, Wh2, out);
}

// Round 8
// 54.585 us; speedup vs baseline: 1.5879x; 1.5879x over previous
//
#include <hip/hip_runtime.h>
#include <stdint.h>

#define NB   8
#define NN   2048
#define FIN  128
#define FOUT 64

__device__ __forceinline__ uint32_t rotl32(uint32_t x, uint32_t r) {
  return (x << r) | (x >> (32u - r));
}

// JAX threefry2x32 with key = (0, 42)
__device__ __forceinline__ void threefry_0_42(uint32_t x0, uint32_t x1,
                                              uint32_t& o0, uint32_t& o1) {
  const uint32_t k0 = 0u, k1 = 42u;
  const uint32_t k2 = 0x1BD11BDAu ^ k0 ^ k1;
  x0 += k0; x1 += k1;
#define TFR(r) { x0 += x1; x1 = rotl32(x1, r); x1 ^= x0; }
  TFR(13u) TFR(15u) TFR(26u) TFR(6u)   x0 += k1; x1 += k2 + 1u;
  TFR(17u) TFR(29u) TFR(16u) TFR(24u)  x0 += k2; x1 += k0 + 2u;
  TFR(13u) TFR(15u) TFR(26u) TFR(6u)   x0 += k0; x1 += k1 + 3u;
  TFR(17u) TFR(29u) TFR(16u) TFR(24u)  x0 += k1; x1 += k2 + 4u;
  TFR(13u) TFR(15u) TFR(26u) TFR(6u)   x0 += k2; x1 += k0 + 5u;
#undef TFR
  o0 = x0; o1 = x1;
}

// Partitionable threefry: bits = o0^o1 of threefry(key, 0, v); keep iff bit31==0.
__device__ __forceinline__ bool keep_bit(uint32_t v) {
  uint32_t o0, o1;
  threefry_0_42(0u, v, o0, o1);
  return !((o0 ^ o1) >> 31);
}

// Kernel A: Wh = h @ W, Wh1 = Wh@a[:64], Wh2 = Wh@a[64:]
// 4 rows/wave, scalar accumulators (W LDS read amortized x4, no spill risk).
__global__ __launch_bounds__(256) void wh_kernel(
    const float* __restrict__ h, const float* __restrict__ W,
    const float* __restrict__ a, float* __restrict__ Wh,
    float* __restrict__ Wh1, float* __restrict__ Wh2) {
  __shared__ __align__(16) float wLds[FIN * FOUT];   // 32 KB
  __shared__ __align__(16) float hLds[16][FIN];      // 8 KB
  const int t = threadIdx.x;
  const int wv = t >> 6, lane = t & 63;
  const int rbase = blockIdx.x * 16;
  {
    const float4* W4 = reinterpret_cast<const float4*>(W);
    float4* wL4 = reinterpret_cast<float4*>(wLds);
    for (int idx = t; idx < FIN * FOUT / 4; idx += 256) wL4[idx] = W4[idx];
    const float4* h4 = reinterpret_cast<const float4*>(h + (size_t)rbase * FIN);
    float4* hL4 = reinterpret_cast<float4*>(&hLds[0][0]);
    for (int idx = t; idx < 16 * FIN / 4; idx += 256) hL4[idx] = h4[idx];
  }
  __syncthreads();
  const int r0 = wv * 4;
  float acc0 = 0.f, acc1 = 0.f, acc2 = 0.f, acc3 = 0.f;
#pragma unroll 4
  for (int k = 0; k < FIN; ++k) {
    const float w = wLds[k * FOUT + lane];   // lanes consecutive: 2-way, free
    acc0 += hLds[r0 + 0][k] * w;             // broadcasts
    acc1 += hLds[r0 + 1][k] * w;
    acc2 += hLds[r0 + 2][k] * w;
    acc3 += hLds[r0 + 3][k] * w;
  }
  const float a1 = a[lane], a2 = a[FOUT + lane];
  float accs[4] = {acc0, acc1, acc2, acc3};
#pragma unroll
  for (int r = 0; r < 4; ++r) {
    const int row = rbase + r0 + r;
    Wh[(size_t)row * FOUT + lane] = accs[r];
    float x1 = accs[r] * a1, x2 = accs[r] * a2;
#pragma unroll
    for (int off = 32; off >= 1; off >>= 1) {
      x1 += __shfl_xor(x1, off);
      x2 += __shfl_xor(x2, off);
    }
    if (lane == 0) { Wh1[row] = x1; Wh2[row] = x2; }
  }
}

// Kernel B: ONE ROW per 256-thread block; 4 waves each own a 512-elem quarter.
//   Per thread only 4 loads (2 int4 + 2 float4) -> TLP hides latency even if
//   the compiler serializes loads (round-7 lesson: VGPR-minimizing codegen).
//   Unconditional LR+exp (round-4/5/6 lesson: divergent gate costs more).
//   Tail per wave: capture survivor j's one-per-lane, ONE lane-parallel
//   threefry, gather-recompute p, ballot-walk kept survivors for PV.
__global__ __launch_bounds__(256) void attn_kernel(
    const int* __restrict__ adj, const float* __restrict__ Wh,
    const float* __restrict__ Wh1, const float* __restrict__ Wh2,
    float* __restrict__ out) {
  __shared__ float redm[4], reds[4];
  __shared__ float accL[4][FOUT];     // 1 KB

  const int r = blockIdx.x;           // row = b*NN + i, [0, 16384)
  const int b = r >> 11;
  const int t = threadIdx.x;
  const int wv = t >> 6, lane = t & 63;
  const int q0 = wv * 512;            // this wave's quarter

  const float wh1 = Wh1[r];
  const int*   arow = adj + (size_t)r * NN;
  const float* wrow = Wh2 + (size_t)b * NN;

  // 4 straight-line loads (two dense 1 KB segments per wave-instruction)
  const int4   aA = *reinterpret_cast<const int4*>(arow + q0 + lane * 4);
  const int4   aB = *reinterpret_cast<const int4*>(arow + q0 + 256 + lane * 4);
  const float4 wA = *reinterpret_cast<const float4*>(wrow + q0 + lane * 4);
  const float4 wB = *reinterpret_cast<const float4*>(wrow + q0 + 256 + lane * 4);

  float ww[8];
  ww[0] = (aA.x > 0) ? wA.x : -1.0e30f;
  ww[1] = (aA.y > 0) ? wA.y : -1.0e30f;
  ww[2] = (aA.z > 0) ? wA.z : -1.0e30f;
  ww[3] = (aA.w > 0) ? wA.w : -1.0e30f;
  ww[4] = (aB.x > 0) ? wB.x : -1.0e30f;
  ww[5] = (aB.y > 0) ? wB.y : -1.0e30f;
  ww[6] = (aB.z > 0) ? wB.z : -1.0e30f;
  ww[7] = (aB.w > 0) ? wB.w : -1.0e30f;

  float mW = fmaxf(fmaxf(fmaxf(ww[0], ww[1]), fmaxf(ww[2], ww[3])),
                   fmaxf(fmaxf(ww[4], ww[5]), fmaxf(ww[6], ww[7])));
#pragma unroll
  for (int off = 1; off < 64; off <<= 1) mW = fmaxf(mW, __shfl_xor(mW, off));
  if (lane == 0) redm[wv] = mW;
  __syncthreads();
  mW = fmaxf(fmaxf(redm[0], redm[1]), fmaxf(redm[2], redm[3]));

  const float me_arg = wh1 + mW;
  const float me = (me_arg < 0.f) ? 0.2f * me_arg : me_arg;   // row max of e

  // unconditional exp; per-lane 8-bit survivor mask
  float s = 0.f;
  uint32_t sm = 0;
#pragma unroll
  for (int k = 0; k < 8; ++k) {
    float z = wh1 + ww[k];
    z = (z < 0.f) ? 0.2f * z : z;
    const float p = __expf(z - me);    // masked (-1e30) underflows to 0
    s += p;
    sm |= (p > 1e-10f) ? (1u << k) : 0u;
  }
#pragma unroll
  for (int off = 1; off < 64; off <<= 1) s += __shfl_xor(s, off);
  if (lane == 0) reds[wv] = s;
  __syncthreads();
  s = reds[0] + reds[1] + reds[2] + reds[3];
  const float inv = 2.0f / s;          // dropout 1/(1-p)=2 folded in

  // capture survivors of this wave's quarter: lane k gets k-th survivor's j
  int myj = -1;
  int ns = 0;
  unsigned long long lm = __ballot(sm != 0u);
  while (lm) {
    const int src = __builtin_ctzll(lm);
    lm &= lm - 1;
    uint32_t srcm = (uint32_t)__shfl((int)sm, src);
    while (srcm) {
      const int bit = __builtin_ctz(srcm);
      srcm &= srcm - 1;
      const int j = q0 + ((bit >> 2) << 8) + (src << 2) + (bit & 3);
      if (lane == ns) myj = j;          // cndmask, no branch
      ++ns;
    }
  }

  // lane-parallel survivor processing: one threefry for the whole wave
  float pk = 0.f;
  {
    const int jj0 = (myj < 0) ? 0 : myj;
    const bool kp = keep_bit(((uint32_t)r << 11) | (uint32_t)jj0);
    float z = wh1 + wrow[jj0];          // tiny gather, L2
    z = (z < 0.f) ? 0.2f * z : z;
    pk = (myj >= 0 && kp) ? __expf(z - me) * inv : 0.f;
  }

  // PV walk over kept survivors (~0.75 per wave)
  float acc = 0.f;
  unsigned long long km = __ballot(pk != 0.f);
  while (km) {
    const int k = __builtin_ctzll(km);
    km &= km - 1;
    const int jj = __shfl(myj, k);
    const float cc = __shfl(pk, k);
    acc += cc * Wh[((size_t)(b * NN + jj)) * FOUT + lane];
  }
  accL[wv][lane] = acc;
  __syncthreads();
  if (t < FOUT) {
    out[(size_t)r * FOUT + t] = accL[0][t] + accL[1][t] + accL[2][t] + accL[3][t];
  }
}

extern "C" void kernel_launch(void* const* d_in, const int* in_sizes, int n_in,
                              void* d_out, int out_size, void* d_ws, size_t ws_size,
                              hipStream_t stream) {
  const float* h   = (const float*)d_in[0];
  const int*   adj = (const int*)d_in[1];
  const float* W   = (const float*)d_in[2];
  const float* a   = (const float*)d_in[3];
  float* out = (float*)d_out;
  float* ws  = (float*)d_ws;

  float* Wh  = ws;                                 // 16384*64 floats
  float* Wh1 = ws + (size_t)NB * NN * FOUT;        // 16384
  float* Wh2 = Wh1 + NB * NN;                      // 16384

  wh_kernel<<<dim3((NB * NN) / 16), dim3(256), 0, stream>>>(h, W, a, Wh, Wh1, Wh2);
  attn_kernel<<<dim3(NB * NN), dim3(256), 0, stream>>>(adj, Wh, Wh1, Wh2, out);
}